// Round 1
// baseline (507.619 us; speedup 1.0000x reference)
//
#include <hip/hip_runtime.h>
#include <cstdint>
#include <cstddef>

// Problem constants (B,S,E,H)=(2,2048,2048,16), D=128, RD=128 (full-rotary)
#define Bd 2
#define Sd 2048
#define Ed 2048
#define Hd 16
#define Dd 128
#define N3E 6144
#define ATT_SCALE 0.08838834764831845f   // 1/sqrt(128)

typedef short bf16x8 __attribute__((ext_vector_type(8)));
typedef float f32x4 __attribute__((ext_vector_type(4)));

__device__ __forceinline__ float bf2f(unsigned short u) {
    union { unsigned int u; float f; } c;
    c.u = ((unsigned int)u) << 16;
    return c.f;
}
__device__ __forceinline__ unsigned short f2bf(float f) {
    union { float f; unsigned int u; } c;
    c.f = f;
    unsigned int x = c.u;
    x += 0x7FFFu + ((x >> 16) & 1u);   // RTNE (finite values only)
    return (unsigned short)(x >> 16);
}

__device__ __forceinline__ void gl2lds16(const void* g, void* l) {
    __builtin_amdgcn_global_load_lds(
        (const __attribute__((address_space(1))) void*)g,
        (__attribute__((address_space(3))) void*)l, 16, 0, 0);
}

// ---------------- fp32 -> bf16 convert ----------------
__global__ void cvt_f32_bf16(const float* __restrict__ src,
                             unsigned short* __restrict__ dst, int n) {
    int i = (blockIdx.x * 256 + threadIdx.x) * 4;
    if (i >= n) return;
    const float4 v = *(const float4*)(src + i);
    dst[i + 0] = f2bf(v.x);
    dst[i + 1] = f2bf(v.y);
    dst[i + 2] = f2bf(v.z);
    dst[i + 3] = f2bf(v.w);
}

// ---------------- bf16 MFMA GEMM, C = A * B^T + bias ----------------
// A: M x K (K contig), Bm: N x K (K contig). 128x128 tile, BK=64, 4 waves (2x2 of 64x64).
// XOR-swizzled LDS (8 chunks/row of 16B) so frag ds_read_b128 is 2-way (free).
// MODE 0: fp32 row-major out (o0), Ndim cols. MODE 1: qkv scatter -> bf16 q/k/v [B,H,S,D].
template <int MODE>
__global__ void gemm_bt(const unsigned short* __restrict__ A,
                        const unsigned short* __restrict__ Bm,
                        const float* __restrict__ bias,
                        void* __restrict__ o0, void* __restrict__ o1,
                        void* __restrict__ o2, int Ndim, int K) {
    __shared__ __align__(16) unsigned short As[128 * 64];
    __shared__ __align__(16) unsigned short Bs[128 * 64];

    const int tid = threadIdx.x;
    const int lane = tid & 63;
    const int wave = tid >> 6;
    const int quad = lane >> 4;
    const int l16 = lane & 15;
    const int wr = wave >> 1;
    const int wc = wave & 1;

    const int n0 = blockIdx.x * 128;
    const int m0 = blockIdx.y * 128;

    const unsigned short* Ab = A + (size_t)m0 * K;
    const unsigned short* Bb = Bm + (size_t)n0 * K;

    const f32x4 fzero = {0.f, 0.f, 0.f, 0.f};
    f32x4 acc[4][4];
#pragma unroll
    for (int i = 0; i < 4; i++)
#pragma unroll
        for (int j = 0; j < 4; j++) acc[i][j] = fzero;

    for (int k0 = 0; k0 < K; k0 += 64) {
        __syncthreads();
#pragma unroll
        for (int it = 0; it < 4; ++it) {
            int L = it * 256 + tid;
            int row = L >> 3;
            int cs = L & 7;
            int gc = cs ^ (row & 7);
            gl2lds16(Ab + row * K + k0 + gc * 8, (void*)(As + L * 8));
            gl2lds16(Bb + row * K + k0 + gc * 8, (void*)(Bs + L * 8));
        }
        __syncthreads();
#pragma unroll
        for (int kk = 0; kk < 2; ++kk) {
            bf16x8 af[4], bfr[4];
#pragma unroll
            for (int i = 0; i < 4; i++) {
                int row = wr * 64 + i * 16 + l16;
                int cs = kk * 4 + quad;
                af[i] = *(const bf16x8*)(As + row * 64 + (cs ^ (row & 7)) * 8);
            }
#pragma unroll
            for (int j = 0; j < 4; j++) {
                int row = wc * 64 + j * 16 + l16;
                int cs = kk * 4 + quad;
                bfr[j] = *(const bf16x8*)(Bs + row * 64 + (cs ^ (row & 7)) * 8);
            }
#pragma unroll
            for (int i = 0; i < 4; i++)
#pragma unroll
                for (int j = 0; j < 4; j++)
                    acc[i][j] = __builtin_amdgcn_mfma_f32_16x16x32_bf16(
                        af[i], bfr[j], acc[i][j], 0, 0, 0);
        }
    }

#pragma unroll
    for (int j = 0; j < 4; j++) {
        int col = n0 + wc * 64 + j * 16 + l16;
        float bv = bias[col];
#pragma unroll
        for (int i = 0; i < 4; i++) {
            int rbase = m0 + wr * 64 + i * 16 + quad * 4;
#pragma unroll
            for (int r = 0; r < 4; r++) {
                float val = acc[i][j][r] + bv;
                int row = rbase + r;
                if (MODE == 0) {
                    ((float*)o0)[(size_t)row * Ndim + col] = val;
                } else {
                    int b = row >> 11;
                    int s = row & 2047;
                    int c = col >> 11;          // 0=q 1=k 2=v
                    int h = (col >> 7) & 15;
                    int d = col & 127;
                    unsigned short* dst = (c == 0) ? (unsigned short*)o0
                                        : (c == 1) ? (unsigned short*)o1
                                                   : (unsigned short*)o2;
                    dst[((size_t)(b * Hd + h) * Sd + s) * Dd + d] = f2bf(val);
                }
            }
        }
    }
}

// ---------------- RoPE in-place on q,k [B,H,S,D] bf16 ----------------
__global__ void rope_qk(unsigned short* __restrict__ q,
                        unsigned short* __restrict__ k) {
    int idx = blockIdx.x * 256 + threadIdx.x;
    const int half = Bd * Hd * Sd * 64;   // 4,194,304 pairs per tensor
    unsigned short* p = (idx < half) ? q : k;
    int i = (idx < half) ? idx : idx - half;
    int j = i & 63;
    int s = (i >> 6) & (Sd - 1);
    int bh = i >> 17;
    int base = (bh * Sd + s) * Dd;
    // inv_freq = 10000^(-2j/128) = exp(-j * ln(1e4)/64)
    float inv_freq = __expf(-(float)j * (9.210340371976184f / 64.0f));
    float fr = (float)s * inv_freq;
    float sn, cs;
    sincosf(fr, &sn, &cs);
    float v1 = bf2f(p[base + j]);
    float v2 = bf2f(p[base + j + 64]);
    p[base + j] = f2bf(v1 * cs - v2 * sn);
    p[base + j + 64] = f2bf(v1 * sn + v2 * cs);
}

// ---------------- V [B,H,S,D] -> Vt [B,H,D,S] ----------------
__global__ void transpose_v(const unsigned short* __restrict__ v,
                            unsigned short* __restrict__ vt) {
    __shared__ unsigned short t[32][33];
    int bh = blockIdx.z;
    int s0 = blockIdx.x * 32;
    int d0 = blockIdx.y * 32;
    int tx = threadIdx.x, ty = threadIdx.y;
    const unsigned short* src = v + ((size_t)bh * Sd + s0) * Dd + d0;
    for (int r = ty; r < 32; r += 8) t[r][tx] = src[(size_t)r * Dd + tx];
    __syncthreads();
    unsigned short* dst = vt + ((size_t)bh * Dd + d0) * Sd + s0;
    for (int r = ty; r < 32; r += 8) dst[(size_t)r * Sd + tx] = t[tx][r];
}

// ---------------- flash attention (causal, online softmax) ----------------
// block = 4 waves, 128 Q rows (32/wave), BN=128 K/V cols, D=128.
// Verified layouts: A-op A[m=lane&15][k=quad*8+j]; C/D col=lane&15,row=quad*4+reg.
__global__ __launch_bounds__(256, 1) void flash_attn(
    const unsigned short* __restrict__ q, const unsigned short* __restrict__ k,
    const unsigned short* __restrict__ vt, unsigned short* __restrict__ ctx) {
    __shared__ __align__(16) unsigned short Ks[128 * 128];
    __shared__ __align__(16) unsigned short Vts[128 * 128];
    __shared__ __align__(16) unsigned short QPs[128 * 136];  // Qs (swizzled) then Ps (pad 136)

    const int tid = threadIdx.x;
    const int lane = tid & 63;
    const int wave = tid >> 6;
    const int quad = lane >> 4;
    const int l16 = lane & 15;
    const int rw0 = wave * 32;

    const int qi = blockIdx.x;
    const int bh = blockIdx.y;
    const int q0 = qi * 128;

    const unsigned short* qb = q + ((size_t)bh * Sd + q0) * Dd;
    const unsigned short* kb = k + (size_t)bh * Sd * Dd;
    const unsigned short* vtb = vt + (size_t)bh * Dd * Sd;

    // stage Q tile (16 chunks/row, XOR swizzle by row&15)
#pragma unroll
    for (int it = 0; it < 8; ++it) {
        int L = it * 256 + tid;
        int row = L >> 4;
        int cs = L & 15;
        int gc = cs ^ (row & 15);
        gl2lds16(qb + row * Dd + gc * 8, (void*)(QPs + L * 8));
    }
    __syncthreads();
    bf16x8 aq[2][4];
#pragma unroll
    for (int i = 0; i < 2; i++)
#pragma unroll
        for (int kk = 0; kk < 4; kk++) {
            int row = rw0 + i * 16 + l16;
            aq[i][kk] = *(const bf16x8*)(QPs + row * 128 +
                                         ((kk * 4 + quad) ^ (row & 15)) * 8);
        }
    __syncthreads();  // all waves done with Qs before Ps overwrites region

    const f32x4 fzero = {0.f, 0.f, 0.f, 0.f};
    f32x4 o[2][8];
#pragma unroll
    for (int i = 0; i < 2; i++)
#pragma unroll
        for (int jd = 0; jd < 8; jd++) o[i][jd] = fzero;
    float mi[2][4], li[2][4];
#pragma unroll
    for (int i = 0; i < 2; i++)
#pragma unroll
        for (int r = 0; r < 4; r++) {
            mi[i][r] = -3.0e38f;
            li[i][r] = 0.f;
        }

    for (int t0 = 0; t0 <= q0; t0 += 128) {
        // stage K tile [t][d] and Vt tile [d][t], both XOR-swizzled
#pragma unroll
        for (int it = 0; it < 8; ++it) {
            int L = it * 256 + tid;
            int row = L >> 4;
            int cs = L & 15;
            int gc = cs ^ (row & 15);
            gl2lds16(kb + (size_t)(t0 + row) * Dd + gc * 8, (void*)(Ks + L * 8));
            gl2lds16(vtb + (size_t)row * Sd + t0 + gc * 8, (void*)(Vts + L * 8));
        }
        __syncthreads();

        // S = Q K^T
        f32x4 sa[2][8];
#pragma unroll
        for (int i = 0; i < 2; i++)
#pragma unroll
            for (int j = 0; j < 8; j++) sa[i][j] = fzero;
#pragma unroll
        for (int kk = 0; kk < 4; kk++) {
            bf16x8 bk[8];
#pragma unroll
            for (int j = 0; j < 8; j++) {
                int row = j * 16 + l16;
                bk[j] = *(const bf16x8*)(Ks + row * 128 +
                                         ((kk * 4 + quad) ^ (row & 15)) * 8);
            }
#pragma unroll
            for (int i = 0; i < 2; i++)
#pragma unroll
                for (int j = 0; j < 8; j++)
                    sa[i][j] = __builtin_amdgcn_mfma_f32_16x16x32_bf16(
                        aq[i][kk], bk[j], sa[i][j], 0, 0, 0);
        }

        // scale + causal mask (diag tile only) + online softmax
        const bool diag = (t0 == q0);
#pragma unroll
        for (int i = 0; i < 2; i++) {
#pragma unroll
            for (int r = 0; r < 4; r++) {
                const int grow = q0 + rw0 + i * 16 + quad * 4 + r;
                float mx = -3.0e38f;
#pragma unroll
                for (int j = 0; j < 8; j++) {
                    float v = sa[i][j][r] * ATT_SCALE;
                    if (diag && (t0 + j * 16 + l16) > grow) v = -3.0e38f;
                    sa[i][j][r] = v;
                    mx = fmaxf(mx, v);
                }
#pragma unroll
                for (int off = 1; off < 16; off <<= 1)
                    mx = fmaxf(mx, __shfl_xor(mx, off, 64));
                const float mnew = fmaxf(mi[i][r], mx);
                const float alpha = __expf(mi[i][r] - mnew);
                float rs = 0.f;
#pragma unroll
                for (int j = 0; j < 8; j++) {
                    float pp = __expf(sa[i][j][r] - mnew);
                    sa[i][j][r] = pp;
                    rs += pp;
                }
#pragma unroll
                for (int off = 1; off < 16; off <<= 1)
                    rs += __shfl_xor(rs, off, 64);
                li[i][r] = li[i][r] * alpha + rs;
                mi[i][r] = mnew;
#pragma unroll
                for (int jd = 0; jd < 8; jd++) o[i][jd][r] *= alpha;
                // P -> LDS (C-layout write; A-layout read below), stride 136
                const int rl = rw0 + i * 16 + quad * 4 + r;
#pragma unroll
                for (int j = 0; j < 8; j++)
                    QPs[rl * 136 + j * 16 + l16] = f2bf(sa[i][j][r]);
            }
        }
        __syncthreads();

        // O += P * V   (k dim = t, 4 steps of 32)
#pragma unroll
        for (int kk = 0; kk < 4; kk++) {
            bf16x8 ap[2];
#pragma unroll
            for (int i = 0; i < 2; i++) {
                int row = rw0 + i * 16 + l16;
                ap[i] = *(const bf16x8*)(QPs + row * 136 + kk * 32 + quad * 8);
            }
            bf16x8 bv[8];
#pragma unroll
            for (int jd = 0; jd < 8; jd++) {
                int d = jd * 16 + l16;
                bv[jd] = *(const bf16x8*)(Vts + d * 128 +
                                          ((kk * 4 + quad) ^ (d & 15)) * 8);
            }
#pragma unroll
            for (int i = 0; i < 2; i++)
#pragma unroll
                for (int jd = 0; jd < 8; jd++)
                    o[i][jd] = __builtin_amdgcn_mfma_f32_16x16x32_bf16(
                        ap[i], bv[jd], o[i][jd], 0, 0, 0);
        }
        __syncthreads();
    }

    // epilogue: ctx[b, s, h*D+d] = O / l   (bf16)
    const int b = bh >> 4;
    const int h = bh & 15;
#pragma unroll
    for (int i = 0; i < 2; i++) {
#pragma unroll
        for (int r = 0; r < 4; r++) {
            const int grow = q0 + rw0 + i * 16 + quad * 4 + r;
            const float inv = 1.0f / li[i][r];
            unsigned short* dst = ctx + ((size_t)(b * Sd + grow)) * Ed + h * Dd;
#pragma unroll
            for (int jd = 0; jd < 8; jd++)
                dst[jd * 16 + l16] = f2bf(o[i][jd][r] * inv);
        }
    }
}

extern "C" void kernel_launch(void* const* d_in, const int* in_sizes, int n_in,
                              void* d_out, int out_size, void* d_ws,
                              size_t ws_size, hipStream_t stream) {
    const float* x = (const float*)d_in[0];
    const float* wqkv_w = (const float*)d_in[1];
    const float* wqkv_b = (const float*)d_in[2];
    const float* out_w = (const float*)d_in[3];
    const float* out_b = (const float*)d_in[4];
    float* out = (float*)d_out;

    // workspace layout (bytes); total 100,663,296 (96 MiB)
    char* ws = (char*)d_ws;
    unsigned short* xb    = (unsigned short*)(ws + 0);         // 16 MiB, dead after QKV GEMM
    unsigned short* wqkvb = (unsigned short*)(ws + 16777216);  // 24 MiB, dead after QKV GEMM
    unsigned short* owb   = (unsigned short*)(ws + 41943040);  // 8 MiB
    unsigned short* qb    = (unsigned short*)(ws + 50331648);  // 16 MiB
    unsigned short* kb    = (unsigned short*)(ws + 67108864);  // 16 MiB
    unsigned short* vb    = (unsigned short*)(ws + 83886080);  // 16 MiB
    unsigned short* vtb   = (unsigned short*)(ws + 0);         // alias xb
    unsigned short* ctx   = (unsigned short*)(ws + 16777216);  // alias wqkvb

    cvt_f32_bf16<<<8192, 256, 0, stream>>>(x, xb, 8388608);
    cvt_f32_bf16<<<12288, 256, 0, stream>>>(wqkv_w, wqkvb, 12582912);
    cvt_f32_bf16<<<4096, 256, 0, stream>>>(out_w, owb, 4194304);

    // qkv = x @ wqkv_w^T + b  -> scatter q/k/v [B,H,S,D] bf16
    gemm_bt<1><<<dim3(48, 32), 256, 0, stream>>>(xb, wqkvb, wqkv_b, qb, kb, vb,
                                                 N3E, Ed);
    rope_qk<<<32768, 256, 0, stream>>>(qb, kb);
    transpose_v<<<dim3(64, 4, 32), dim3(32, 8), 0, stream>>>(vb, vtb);
    flash_attn<<<dim3(16, 32), 256, 0, stream>>>(qb, kb, vtb, ctx);
    // out = ctx @ out_w^T + b  (fp32)
    gemm_bt<0><<<dim3(16, 32), 256, 0, stream>>>(ctx, owb, out_b, out, nullptr,
                                                 nullptr, Ed, Ed);
}

// Round 2
// 506.318 us; speedup vs baseline: 1.0026x; 1.0026x over previous
//
#include <hip/hip_runtime.h>
#include <cstdint>
#include <cstddef>

// Problem constants (B,S,E,H)=(2,2048,2048,16), D=128, RD=128 (full-rotary)
#define Bd 2
#define Sd 2048
#define Ed 2048
#define Hd 16
#define Dd 128
#define N3E 6144
#define ATT_SCALE 0.08838834764831845f   // 1/sqrt(128)

typedef short bf16x8 __attribute__((ext_vector_type(8)));
typedef float f32x4 __attribute__((ext_vector_type(4)));

__device__ __forceinline__ float bf2f(unsigned short u) {
    union { unsigned int u; float f; } c;
    c.u = ((unsigned int)u) << 16;
    return c.f;
}
__device__ __forceinline__ unsigned short f2bf(float f) {
    union { float f; unsigned int u; } c;
    c.f = f;
    unsigned int x = c.u;
    x += 0x7FFFu + ((x >> 16) & 1u);   // RTNE (finite values only)
    return (unsigned short)(x >> 16);
}

__device__ __forceinline__ void gl2lds16(const void* g, void* l) {
    __builtin_amdgcn_global_load_lds(
        (const __attribute__((address_space(1))) void*)g,
        (__attribute__((address_space(3))) void*)l, 16, 0, 0);
}

// ---------------- fp32 -> bf16 convert ----------------
__global__ void cvt_f32_bf16(const float* __restrict__ src,
                             unsigned short* __restrict__ dst, int n) {
    int i = (blockIdx.x * 256 + threadIdx.x) * 4;
    if (i >= n) return;
    const float4 v = *(const float4*)(src + i);
    dst[i + 0] = f2bf(v.x);
    dst[i + 1] = f2bf(v.y);
    dst[i + 2] = f2bf(v.z);
    dst[i + 3] = f2bf(v.w);
}

// ---------------- bf16 MFMA GEMM, C = A * B^T + bias ----------------
// A: M x K (K contig), Bm: N x K (K contig). 128x128 tile, BK=64, 4 waves (2x2 of 64x64).
// XOR-swizzled LDS (8 chunks/row of 16B) so frag ds_read_b128 is 2-way (free).
// MODE 0: fp32 row-major out (o0), Ndim cols.
// MODE 1: qkv scatter -> q[B,H,S,D], k[B,H,S,D], v TRANSPOSED -> [B,H,D,S] (all bf16).
template <int MODE>
__global__ void gemm_bt(const unsigned short* __restrict__ A,
                        const unsigned short* __restrict__ Bm,
                        const float* __restrict__ bias,
                        void* __restrict__ o0, void* __restrict__ o1,
                        void* __restrict__ o2, int Ndim, int K) {
    __shared__ __align__(16) unsigned short As[128 * 64];
    __shared__ __align__(16) unsigned short Bs[128 * 64];

    const int tid = threadIdx.x;
    const int lane = tid & 63;
    const int wave = tid >> 6;
    const int quad = lane >> 4;
    const int l16 = lane & 15;
    const int wr = wave >> 1;
    const int wc = wave & 1;

    const int n0 = blockIdx.x * 128;
    const int m0 = blockIdx.y * 128;

    const unsigned short* Ab = A + (size_t)m0 * K;
    const unsigned short* Bb = Bm + (size_t)n0 * K;

    const f32x4 fzero = {0.f, 0.f, 0.f, 0.f};
    f32x4 acc[4][4];
#pragma unroll
    for (int i = 0; i < 4; i++)
#pragma unroll
        for (int j = 0; j < 4; j++) acc[i][j] = fzero;

    for (int k0 = 0; k0 < K; k0 += 64) {
        __syncthreads();
#pragma unroll
        for (int it = 0; it < 4; ++it) {
            int L = it * 256 + tid;
            int row = L >> 3;
            int cs = L & 7;
            int gc = cs ^ (row & 7);
            gl2lds16(Ab + row * K + k0 + gc * 8, (void*)(As + L * 8));
            gl2lds16(Bb + row * K + k0 + gc * 8, (void*)(Bs + L * 8));
        }
        __syncthreads();
#pragma unroll
        for (int kk = 0; kk < 2; ++kk) {
            bf16x8 af[4], bfr[4];
#pragma unroll
            for (int i = 0; i < 4; i++) {
                int row = wr * 64 + i * 16 + l16;
                int cs = kk * 4 + quad;
                af[i] = *(const bf16x8*)(As + row * 64 + (cs ^ (row & 7)) * 8);
            }
#pragma unroll
            for (int j = 0; j < 4; j++) {
                int row = wc * 64 + j * 16 + l16;
                int cs = kk * 4 + quad;
                bfr[j] = *(const bf16x8*)(Bs + row * 64 + (cs ^ (row & 7)) * 8);
            }
#pragma unroll
            for (int i = 0; i < 4; i++)
#pragma unroll
                for (int j = 0; j < 4; j++)
                    acc[i][j] = __builtin_amdgcn_mfma_f32_16x16x32_bf16(
                        af[i], bfr[j], acc[i][j], 0, 0, 0);
        }
    }

#pragma unroll
    for (int j = 0; j < 4; j++) {
        int col = n0 + wc * 64 + j * 16 + l16;
        float bv = bias[col];
#pragma unroll
        for (int i = 0; i < 4; i++) {
            int rbase = m0 + wr * 64 + i * 16 + quad * 4;
#pragma unroll
            for (int r = 0; r < 4; r++) {
                float val = acc[i][j][r] + bv;
                int row = rbase + r;
                if (MODE == 0) {
                    ((float*)o0)[(size_t)row * Ndim + col] = val;
                } else {
                    int b = row >> 11;
                    int s = row & 2047;
                    int c = col >> 11;          // 0=q 1=k 2=v
                    int h = (col >> 7) & 15;
                    int d = col & 127;
                    if (c == 2) {
                        // V stored transposed: [B,H,D,S]
                        ((unsigned short*)o2)[((size_t)(b * Hd + h) * Dd + d) * Sd + s] =
                            f2bf(val);
                    } else {
                        unsigned short* dst =
                            (c == 0) ? (unsigned short*)o0 : (unsigned short*)o1;
                        dst[((size_t)(b * Hd + h) * Sd + s) * Dd + d] = f2bf(val);
                    }
                }
            }
        }
    }
}

// ---------------- RoPE in-place on q,k [B,H,S,D] bf16 ----------------
__global__ void rope_qk(unsigned short* __restrict__ q,
                        unsigned short* __restrict__ k) {
    int idx = blockIdx.x * 256 + threadIdx.x;
    const int half = Bd * Hd * Sd * 64;   // 4,194,304 pairs per tensor
    unsigned short* p = (idx < half) ? q : k;
    int i = (idx < half) ? idx : idx - half;
    int j = i & 63;
    int s = (i >> 6) & (Sd - 1);
    int bh = i >> 17;
    int base = (bh * Sd + s) * Dd;
    // inv_freq = 10000^(-2j/128) = exp(-j * ln(1e4)/64)
    float inv_freq = __expf(-(float)j * (9.210340371976184f / 64.0f));
    float fr = (float)s * inv_freq;
    float sn, cs;
    __sincosf(fr, &sn, &cs);
    float v1 = bf2f(p[base + j]);
    float v2 = bf2f(p[base + j + 64]);
    p[base + j] = f2bf(v1 * cs - v2 * sn);
    p[base + j + 64] = f2bf(v1 * sn + v2 * cs);
}

// ---------------- flash attention (causal, online softmax) ----------------
// BM=64 Q rows (16/wave), BN=64 K/V cols, D=128. LDS = 48 KB -> 3 blocks/CU.
// Verified layouts: A-op A[m=lane&15][k=quad*8+j]; B-op B[n=lane&15][k=quad*8+j];
// C/D col=lane&15, row=quad*4+reg.
__global__ __launch_bounds__(256, 3) void flash_attn(
    const unsigned short* __restrict__ q, const unsigned short* __restrict__ k,
    const unsigned short* __restrict__ vt, unsigned short* __restrict__ ctx) {
    __shared__ __align__(16) unsigned short Ks[64 * 128];    // 16 KB [t][d] swizzled
    __shared__ __align__(16) unsigned short Vts[128 * 64];   // 16 KB [d][t] swizzled
    __shared__ __align__(16) unsigned short QPs[64 * 128];   // 16 KB: Q staging, then P (stride 72)

    const int tid = threadIdx.x;
    const int lane = tid & 63;
    const int wave = tid >> 6;
    const int quad = lane >> 4;
    const int l16 = lane & 15;
    const int rw0 = wave * 16;

    const int qi = blockIdx.x;
    const int bh = blockIdx.y;
    const int q0 = qi * 64;

    const unsigned short* qb = q + ((size_t)bh * Sd + q0) * Dd;
    const unsigned short* kb = k + (size_t)bh * Sd * Dd;
    const unsigned short* vtb = vt + (size_t)bh * Dd * Sd;

    // stage Q tile: 64 rows x 16 chunks of 16B, XOR swizzle by row&15
#pragma unroll
    for (int it = 0; it < 4; ++it) {
        int L = it * 256 + tid;
        int row = L >> 4;
        int cs = L & 15;
        int gc = cs ^ (row & 15);
        gl2lds16(qb + row * Dd + gc * 8, (void*)(QPs + L * 8));
    }
    __syncthreads();
    bf16x8 aq[4];
#pragma unroll
    for (int kk = 0; kk < 4; kk++) {
        int row = rw0 + l16;
        aq[kk] = *(const bf16x8*)(QPs + row * 128 + ((kk * 4 + quad) ^ (row & 15)) * 8);
    }
    __syncthreads();  // all waves done with Q staging before P overwrites region

    const f32x4 fzero = {0.f, 0.f, 0.f, 0.f};
    f32x4 o[8];
#pragma unroll
    for (int jd = 0; jd < 8; jd++) o[jd] = fzero;
    float mi[4], li[4];
#pragma unroll
    for (int r = 0; r < 4; r++) {
        mi[r] = -3.0e38f;
        li[r] = 0.f;
    }

    for (int t0 = 0; t0 <= q0; t0 += 64) {
        // stage K tile [t][d] (64x16 chunks) and Vt tile [d][t] (128x8 chunks)
#pragma unroll
        for (int it = 0; it < 4; ++it) {
            int L = it * 256 + tid;
            int rk = L >> 4;
            int ck = L & 15;
            int gk = ck ^ (rk & 15);
            gl2lds16(kb + (size_t)(t0 + rk) * Dd + gk * 8, (void*)(Ks + L * 8));
            int rv = L >> 3;
            int cv = L & 7;
            int gv = cv ^ (rv & 7);
            gl2lds16(vtb + (size_t)rv * Sd + t0 + gv * 8, (void*)(Vts + L * 8));
        }
        __syncthreads();

        // S = Q K^T  (16 rows x 64 cols per wave)
        f32x4 sa[4];
#pragma unroll
        for (int j = 0; j < 4; j++) sa[j] = fzero;
#pragma unroll
        for (int kk = 0; kk < 4; kk++) {
            bf16x8 bk[4];
#pragma unroll
            for (int j = 0; j < 4; j++) {
                int rowt = j * 16 + l16;
                bk[j] = *(const bf16x8*)(Ks + rowt * 128 +
                                         ((kk * 4 + quad) ^ (rowt & 15)) * 8);
            }
#pragma unroll
            for (int j = 0; j < 4; j++)
                sa[j] = __builtin_amdgcn_mfma_f32_16x16x32_bf16(aq[kk], bk[j],
                                                                sa[j], 0, 0, 0);
        }

        // scale + causal mask (diag tile only) + online softmax
        const bool masked = (t0 == q0);
#pragma unroll
        for (int r = 0; r < 4; r++) {
            const int grow = q0 + rw0 + quad * 4 + r;
            float mx = -3.0e38f;
#pragma unroll
            for (int j = 0; j < 4; j++) {
                float v = sa[j][r] * ATT_SCALE;
                if (masked && (t0 + j * 16 + l16) > grow) v = -3.0e38f;
                sa[j][r] = v;
                mx = fmaxf(mx, v);
            }
#pragma unroll
            for (int off = 1; off < 16; off <<= 1)
                mx = fmaxf(mx, __shfl_xor(mx, off, 64));
            const float mnew = fmaxf(mi[r], mx);
            const float alpha = __expf(mi[r] - mnew);
            float rs = 0.f;
#pragma unroll
            for (int j = 0; j < 4; j++) {
                float pp = __expf(sa[j][r] - mnew);
                sa[j][r] = pp;
                rs += pp;
            }
#pragma unroll
            for (int off = 1; off < 16; off <<= 1)
                rs += __shfl_xor(rs, off, 64);
            li[r] = li[r] * alpha + rs;
            mi[r] = mnew;
#pragma unroll
            for (int jd = 0; jd < 8; jd++) o[jd][r] *= alpha;
            // P -> LDS (C-layout write; wave-local rows, stride 72 breaks conflicts)
            const int rl = rw0 + quad * 4 + r;
#pragma unroll
            for (int j = 0; j < 4; j++)
                QPs[rl * 72 + j * 16 + l16] = f2bf(sa[j][r]);
        }
        // no barrier: each wave reads back only its own 16 P rows

        // O += P * V  (k dim = t, 2 steps of 32)
#pragma unroll
        for (int kk = 0; kk < 2; kk++) {
            bf16x8 ap = *(const bf16x8*)(QPs + (rw0 + l16) * 72 + kk * 32 + quad * 8);
            bf16x8 bv[8];
#pragma unroll
            for (int jd = 0; jd < 8; jd++) {
                int d = jd * 16 + l16;
                bv[jd] = *(const bf16x8*)(Vts + d * 64 +
                                          ((kk * 4 + quad) ^ (d & 7)) * 8);
            }
#pragma unroll
            for (int jd = 0; jd < 8; jd++)
                o[jd] = __builtin_amdgcn_mfma_f32_16x16x32_bf16(ap, bv[jd],
                                                                o[jd], 0, 0, 0);
        }
        __syncthreads();  // protect Ks/Vts (+P region) before next-tile staging
    }

    // epilogue: ctx[b, s, h*D+d] = O / l   (bf16)
    const int b = bh >> 4;
    const int h = bh & 15;
#pragma unroll
    for (int r = 0; r < 4; r++) {
        const int grow = q0 + rw0 + quad * 4 + r;
        const float inv = 1.0f / li[r];
        unsigned short* dst = ctx + ((size_t)(b * Sd + grow)) * Ed + h * Dd;
#pragma unroll
        for (int jd = 0; jd < 8; jd++)
            dst[jd * 16 + l16] = f2bf(o[jd][r] * inv);
    }
}

extern "C" void kernel_launch(void* const* d_in, const int* in_sizes, int n_in,
                              void* d_out, int out_size, void* d_ws,
                              size_t ws_size, hipStream_t stream) {
    const float* x = (const float*)d_in[0];
    const float* wqkv_w = (const float*)d_in[1];
    const float* wqkv_b = (const float*)d_in[2];
    const float* out_w = (const float*)d_in[3];
    const float* out_b = (const float*)d_in[4];
    float* out = (float*)d_out;

    // workspace layout (bytes); total 100,663,296 (96 MiB)
    char* ws = (char*)d_ws;
    unsigned short* xb    = (unsigned short*)(ws + 0);         // 16 MiB, dead after QKV GEMM
    unsigned short* wqkvb = (unsigned short*)(ws + 16777216);  // 24 MiB, dead after QKV GEMM
    unsigned short* owb   = (unsigned short*)(ws + 41943040);  // 8 MiB
    unsigned short* qb    = (unsigned short*)(ws + 50331648);  // 16 MiB
    unsigned short* kb    = (unsigned short*)(ws + 67108864);  // 16 MiB
    unsigned short* vtb   = (unsigned short*)(ws + 83886080);  // 16 MiB [B,H,D,S]
    unsigned short* ctx   = (unsigned short*)(ws + 0);         // alias xb (dead by then)

    cvt_f32_bf16<<<8192, 256, 0, stream>>>(x, xb, 8388608);
    cvt_f32_bf16<<<12288, 256, 0, stream>>>(wqkv_w, wqkvb, 12582912);
    cvt_f32_bf16<<<4096, 256, 0, stream>>>(out_w, owb, 4194304);

    // qkv = x @ wqkv_w^T + b  -> scatter q/k [B,H,S,D], v -> [B,H,D,S] (bf16)
    gemm_bt<1><<<dim3(48, 32), 256, 0, stream>>>(xb, wqkvb, wqkv_b, qb, kb, vtb,
                                                 N3E, Ed);
    rope_qk<<<32768, 256, 0, stream>>>(qb, kb);
    flash_attn<<<dim3(32, 32), 256, 0, stream>>>(qb, kb, vtb, ctx);
    // out = ctx @ out_w^T + b  (fp32)
    gemm_bt<0><<<dim3(16, 32), 256, 0, stream>>>(ctx, owb, out_b, out, nullptr,
                                                 nullptr, Ed, Ed);
}

// Round 3
// 372.627 us; speedup vs baseline: 1.3623x; 1.3588x over previous
//
#include <hip/hip_runtime.h>
#include <cstdint>
#include <cstddef>

// Problem constants (B,S,E,H)=(2,2048,2048,16), D=128, RD=128 (full-rotary)
#define Bd 2
#define Sd 2048
#define Ed 2048
#define Hd 16
#define Dd 128
#define N3E 6144
#define ATT_SCALE 0.08838834764831845f   // 1/sqrt(128)

typedef short bf16x8 __attribute__((ext_vector_type(8)));
typedef float f32x4 __attribute__((ext_vector_type(4)));

__device__ __forceinline__ float bf2f(unsigned short u) {
    union { unsigned int u; float f; } c;
    c.u = ((unsigned int)u) << 16;
    return c.f;
}
__device__ __forceinline__ unsigned short f2bf(float f) {
    union { float f; unsigned int u; } c;
    c.f = f;
    unsigned int x = c.u;
    x += 0x7FFFu + ((x >> 16) & 1u);   // RTNE (finite values only)
    return (unsigned short)(x >> 16);
}

__device__ __forceinline__ void gl2lds16(const void* g, void* l) {
    __builtin_amdgcn_global_load_lds(
        (const __attribute__((address_space(1))) void*)g,
        (__attribute__((address_space(3))) void*)l, 16, 0, 0);
}

// ---------------- fp32 -> bf16 convert ----------------
__global__ void cvt_f32_bf16(const float* __restrict__ src,
                             unsigned short* __restrict__ dst, int n) {
    int i = (blockIdx.x * 256 + threadIdx.x) * 4;
    if (i >= n) return;
    const float4 v = *(const float4*)(src + i);
    dst[i + 0] = f2bf(v.x);
    dst[i + 1] = f2bf(v.y);
    dst[i + 2] = f2bf(v.z);
    dst[i + 3] = f2bf(v.w);
}

// ---------------- bf16 MFMA GEMM, C = A * B^T + bias ----------------
// A: M x K (K contig), Bm: N x K (K contig). 128x128 tile, BK=64, 4 waves (2x2 of 64x64).
// XOR-swizzled LDS (8 chunks/row of 16B) so frag ds_read_b128 is 2-way (free).
// MODE 0: fp32 row-major out (o0), Ndim cols.
// MODE 1: qkv scatter -> q/k/v [B,H,S,D] bf16 (coalesced d-contiguous stores).
template <int MODE>
__global__ void gemm_bt(const unsigned short* __restrict__ A,
                        const unsigned short* __restrict__ Bm,
                        const float* __restrict__ bias,
                        void* __restrict__ o0, void* __restrict__ o1,
                        void* __restrict__ o2, int Ndim, int K) {
    __shared__ __align__(16) unsigned short As[128 * 64];
    __shared__ __align__(16) unsigned short Bs[128 * 64];

    const int tid = threadIdx.x;
    const int lane = tid & 63;
    const int wave = tid >> 6;
    const int quad = lane >> 4;
    const int l16 = lane & 15;
    const int wr = wave >> 1;
    const int wc = wave & 1;

    const int n0 = blockIdx.x * 128;
    const int m0 = blockIdx.y * 128;

    const unsigned short* Ab = A + (size_t)m0 * K;
    const unsigned short* Bb = Bm + (size_t)n0 * K;

    const f32x4 fzero = {0.f, 0.f, 0.f, 0.f};
    f32x4 acc[4][4];
#pragma unroll
    for (int i = 0; i < 4; i++)
#pragma unroll
        for (int j = 0; j < 4; j++) acc[i][j] = fzero;

    for (int k0 = 0; k0 < K; k0 += 64) {
        __syncthreads();
#pragma unroll
        for (int it = 0; it < 4; ++it) {
            int L = it * 256 + tid;
            int row = L >> 3;
            int cs = L & 7;
            int gc = cs ^ (row & 7);
            gl2lds16(Ab + row * K + k0 + gc * 8, (void*)(As + L * 8));
            gl2lds16(Bb + row * K + k0 + gc * 8, (void*)(Bs + L * 8));
        }
        __syncthreads();
#pragma unroll
        for (int kk = 0; kk < 2; ++kk) {
            bf16x8 af[4], bfr[4];
#pragma unroll
            for (int i = 0; i < 4; i++) {
                int row = wr * 64 + i * 16 + l16;
                int cs = kk * 4 + quad;
                af[i] = *(const bf16x8*)(As + row * 64 + (cs ^ (row & 7)) * 8);
            }
#pragma unroll
            for (int j = 0; j < 4; j++) {
                int row = wc * 64 + j * 16 + l16;
                int cs = kk * 4 + quad;
                bfr[j] = *(const bf16x8*)(Bs + row * 64 + (cs ^ (row & 7)) * 8);
            }
#pragma unroll
            for (int i = 0; i < 4; i++)
#pragma unroll
                for (int j = 0; j < 4; j++)
                    acc[i][j] = __builtin_amdgcn_mfma_f32_16x16x32_bf16(
                        af[i], bfr[j], acc[i][j], 0, 0, 0);
        }
    }

#pragma unroll
    for (int j = 0; j < 4; j++) {
        int col = n0 + wc * 64 + j * 16 + l16;
        float bv = bias[col];
#pragma unroll
        for (int i = 0; i < 4; i++) {
            int rbase = m0 + wr * 64 + i * 16 + quad * 4;
#pragma unroll
            for (int r = 0; r < 4; r++) {
                float val = acc[i][j][r] + bv;
                int row = rbase + r;
                if (MODE == 0) {
                    ((float*)o0)[(size_t)row * Ndim + col] = val;
                } else {
                    int b = row >> 11;
                    int s = row & 2047;
                    int c = col >> 11;          // 0=q 1=k 2=v
                    int h = (col >> 7) & 15;
                    int d = col & 127;
                    unsigned short* dst = (c == 0) ? (unsigned short*)o0
                                        : (c == 1) ? (unsigned short*)o1
                                                   : (unsigned short*)o2;
                    dst[((size_t)(b * Hd + h) * Sd + s) * Dd + d] = f2bf(val);
                }
            }
        }
    }
}

// ---------------- RoPE in-place on q,k [B,H,S,D] bf16 ----------------
__global__ void rope_qk(unsigned short* __restrict__ q,
                        unsigned short* __restrict__ k) {
    int idx = blockIdx.x * 256 + threadIdx.x;
    const int half = Bd * Hd * Sd * 64;   // 4,194,304 pairs per tensor
    unsigned short* p = (idx < half) ? q : k;
    int i = (idx < half) ? idx : idx - half;
    int j = i & 63;
    int s = (i >> 6) & (Sd - 1);
    int bh = i >> 17;
    int base = (bh * Sd + s) * Dd;
    // inv_freq = 10000^(-2j/128) = exp(-j * ln(1e4)/64)
    float inv_freq = __expf(-(float)j * (9.210340371976184f / 64.0f));
    float fr = (float)s * inv_freq;
    float sn, cs;
    __sincosf(fr, &sn, &cs);
    float v1 = bf2f(p[base + j]);
    float v2 = bf2f(p[base + j + 64]);
    p[base + j] = f2bf(v1 * cs - v2 * sn);
    p[base + j + 64] = f2bf(v1 * sn + v2 * cs);
}

// ---------------- V [B,H,S,D] -> Vt [B,H,D,S] ----------------
__global__ void transpose_v(const unsigned short* __restrict__ v,
                            unsigned short* __restrict__ vt) {
    __shared__ unsigned short t[32][33];
    int bh = blockIdx.z;
    int s0 = blockIdx.x * 32;
    int d0 = blockIdx.y * 32;
    int tx = threadIdx.x, ty = threadIdx.y;
    const unsigned short* src = v + ((size_t)bh * Sd + s0) * Dd + d0;
    for (int r = ty; r < 32; r += 8) t[r][tx] = src[(size_t)r * Dd + tx];
    __syncthreads();
    unsigned short* dst = vt + ((size_t)bh * Dd + d0) * Sd + s0;
    for (int r = ty; r < 32; r += 8) dst[(size_t)r * Sd + tx] = t[tx][r];
}

// ---------------- flash attention (causal, online softmax) ----------------
// BM=64 (16 q-rows/wave), BN=64, D=128. LDS = 40 KB -> 4 blocks/CU.
// KEY restructure vs R2: compute S^T = K*Q^T so softmax rows live along
// lane&15 (q) with k in registers -> register reductions + 2 shfl_xor total
// (was 4 serial chains of 8). alpha/l broadcast to O layout via 4 bpermute.
// Layouts (verified): A[m=lane&15][k=quad*8+j]; B[n=lane&15][k=quad*8+j];
// C/D row=quad*4+reg, col=lane&15.
__global__ __launch_bounds__(256, 4) void flash_attn(
    const unsigned short* __restrict__ q, const unsigned short* __restrict__ k,
    const unsigned short* __restrict__ vt, unsigned short* __restrict__ ctx) {
    __shared__ __align__(16) unsigned short Ks[64 * 128];   // 16 KB [t][d] swizzled (Q stages here first)
    __shared__ __align__(16) unsigned short Vts[128 * 64];  // 16 KB [d][t] swizzled
    __shared__ __align__(16) unsigned short Ps[64 * 64];    // 8 KB  [q][t] chunk-swizzled

    const int tid = threadIdx.x;
    const int lane = tid & 63;
    const int wave = tid >> 6;
    const int quad = lane >> 4;
    const int l16 = lane & 15;
    const int rw0 = wave * 16;
    const int ql = rw0 + l16;        // this lane's q row (local)
    const int qsw = ql & 7;          // P-region swizzle key

    // balanced qi permutation: under round-robin block->CU placement the 4
    // blocks a CU receives have qi in {31-y0, y0, 23-y0, 8+y0} -> work sum 66
    // (constant). Heaviest quartile (k=0) dispatches first.
    const int yy = blockIdx.y;
    const int kq = yy >> 3, y0 = yy & 7;
    const int qi = (kq == 0) ? 31 - y0 : (kq == 1) ? y0 : (kq == 2) ? 23 - y0 : 8 + y0;
    const int bh = blockIdx.x;
    const int q0 = qi * 64;

    const unsigned short* qb = q + ((size_t)bh * Sd + q0) * Dd;
    const unsigned short* kb = k + (size_t)bh * Sd * Dd;
    const unsigned short* vtb = vt + (size_t)bh * Dd * Sd;

    // stage Q tile through Ks (64 rows x 16 chunks of 16B, XOR swizzle row&15)
#pragma unroll
    for (int it = 0; it < 4; ++it) {
        int L = it * 256 + tid;
        int row = L >> 4;
        int cs = L & 15;
        int gc = cs ^ (row & 15);
        gl2lds16(qb + row * Dd + gc * 8, (void*)(Ks + L * 8));
    }
    __syncthreads();
    bf16x8 aq[4];
#pragma unroll
    for (int kk = 0; kk < 4; kk++)
        aq[kk] = *(const bf16x8*)(Ks + ql * 128 + ((kk * 4 + quad) ^ (ql & 15)) * 8);
    __syncthreads();  // Q frags in registers; Ks free for K tiles

    const f32x4 fzero = {0.f, 0.f, 0.f, 0.f};
    f32x4 o[8];
#pragma unroll
    for (int jd = 0; jd < 8; jd++) o[jd] = fzero;
    float mi = -3.0e38f, li = 0.f;   // per-lane: online-softmax state of q row l16-of-wave

    for (int t0 = 0; t0 <= q0; t0 += 64) {
        // stage K tile [t][d] (16 chunks/row) and Vt tile [d][t] (8 chunks/row)
#pragma unroll
        for (int it = 0; it < 4; ++it) {
            int L = it * 256 + tid;
            int rk = L >> 4;
            int ck = L & 15;
            int gk = ck ^ (rk & 15);
            gl2lds16(kb + (size_t)(t0 + rk) * Dd + gk * 8, (void*)(Ks + L * 8));
            int rv = L >> 3;
            int cv = L & 7;
            int gv = cv ^ (rv & 7);
            gl2lds16(vtb + (size_t)rv * Sd + t0 + gv * 8, (void*)(Vts + L * 8));
        }
        __syncthreads();

        // S^T = K Q^T : sa[j] rows k=j*16+quad*4+r, col q=l16
        f32x4 sa[4];
#pragma unroll
        for (int j = 0; j < 4; j++) sa[j] = fzero;
#pragma unroll
        for (int kk = 0; kk < 4; kk++) {
            bf16x8 bk[4];
#pragma unroll
            for (int j = 0; j < 4; j++) {
                int rowt = j * 16 + l16;
                bk[j] = *(const bf16x8*)(Ks + rowt * 128 +
                                         ((kk * 4 + quad) ^ (rowt & 15)) * 8);
            }
#pragma unroll
            for (int j = 0; j < 4; j++)
                sa[j] = __builtin_amdgcn_mfma_f32_16x16x32_bf16(bk[j], aq[kk],
                                                                sa[j], 0, 0, 0);
        }

        // scale (+ causal mask on diagonal tile)
#pragma unroll
        for (int j = 0; j < 4; j++)
#pragma unroll
            for (int r = 0; r < 4; r++) sa[j][r] *= ATT_SCALE;
        if (t0 == q0) {
            const int qg = rw0 + l16;               // q (tile-local)
#pragma unroll
            for (int j = 0; j < 4; j++)
#pragma unroll
                for (int r = 0; r < 4; r++)
                    if ((j * 16 + quad * 4 + r) > qg) sa[j][r] = -3.0e38f;
        }

        // online softmax: register reduce over 16 k-values, then 2 shfl_xor
        float mx = -3.0e38f;
#pragma unroll
        for (int j = 0; j < 4; j++)
#pragma unroll
            for (int r = 0; r < 4; r++) mx = fmaxf(mx, sa[j][r]);
        mx = fmaxf(mx, __shfl_xor(mx, 16, 64));
        mx = fmaxf(mx, __shfl_xor(mx, 32, 64));
        const float mnew = fmaxf(mi, mx);
        const float alpha = __expf(mi - mnew);
        float rs = 0.f;
#pragma unroll
        for (int j = 0; j < 4; j++)
#pragma unroll
            for (int r = 0; r < 4; r++) {
                float pp = __expf(sa[j][r] - mnew);
                sa[j][r] = pp;
                rs += pp;
            }
        rs += __shfl_xor(rs, 16, 64);
        rs += __shfl_xor(rs, 32, 64);
        li = li * alpha + rs;
        mi = mnew;

        // P store: lane owns row ql, k = j*16+quad*4+{0..3} -> packed b64.
        // chunk c = j*2+(quad>>1), swizzled c^qsw; inner (quad&1)*4 ushorts.
#pragma unroll
        for (int j = 0; j < 4; j++) {
            ushort4 pk;
            pk.x = f2bf(sa[j][0]);
            pk.y = f2bf(sa[j][1]);
            pk.z = f2bf(sa[j][2]);
            pk.w = f2bf(sa[j][3]);
            *(ushort4*)(Ps + ql * 64 + ((j * 2 + (quad >> 1)) ^ qsw) * 8 +
                        (quad & 1) * 4) = pk;
        }

        // broadcast alpha to O layout rows (q = quad*4+r) via bpermute
        float av[4];
#pragma unroll
        for (int r = 0; r < 4; r++) av[r] = __shfl(alpha, quad * 4 + r, 64);
#pragma unroll
        for (int jd = 0; jd < 8; jd++)
#pragma unroll
            for (int r = 0; r < 4; r++) o[jd][r] *= av[r];

        // O += P * V   (wave-local P rows; no barrier needed before reads)
#pragma unroll
        for (int kk = 0; kk < 2; kk++) {
            bf16x8 ap = *(const bf16x8*)(Ps + ql * 64 +
                                         ((kk * 4 + quad) ^ qsw) * 8);
            bf16x8 bv[8];
#pragma unroll
            for (int jd = 0; jd < 8; jd++) {
                int d = jd * 16 + l16;
                bv[jd] = *(const bf16x8*)(Vts + d * 64 +
                                          ((kk * 4 + quad) ^ (d & 7)) * 8);
            }
#pragma unroll
            for (int jd = 0; jd < 8; jd++)
                o[jd] = __builtin_amdgcn_mfma_f32_16x16x32_bf16(ap, bv[jd],
                                                                o[jd], 0, 0, 0);
        }
        __syncthreads();  // protect Ks/Vts before next-tile staging
    }

    // epilogue: ctx[b, s, h*D+d] = O / l   (bf16)
    const int b = bh >> 4;
    const int h = bh & 15;
    float linv[4];
#pragma unroll
    for (int r = 0; r < 4; r++) linv[r] = 1.0f / __shfl(li, quad * 4 + r, 64);
#pragma unroll
    for (int r = 0; r < 4; r++) {
        const int grow = q0 + rw0 + quad * 4 + r;
        unsigned short* dst = ctx + ((size_t)(b * Sd + grow)) * Ed + h * Dd;
#pragma unroll
        for (int jd = 0; jd < 8; jd++)
            dst[jd * 16 + l16] = f2bf(o[jd][r] * linv[r]);
    }
}

extern "C" void kernel_launch(void* const* d_in, const int* in_sizes, int n_in,
                              void* d_out, int out_size, void* d_ws,
                              size_t ws_size, hipStream_t stream) {
    const float* x = (const float*)d_in[0];
    const float* wqkv_w = (const float*)d_in[1];
    const float* wqkv_b = (const float*)d_in[2];
    const float* out_w = (const float*)d_in[3];
    const float* out_b = (const float*)d_in[4];
    float* out = (float*)d_out;

    // workspace layout (bytes); total 100,663,296 (96 MiB)
    char* ws = (char*)d_ws;
    unsigned short* xb    = (unsigned short*)(ws + 0);         // 16 MiB, dead after QKV GEMM
    unsigned short* wqkvb = (unsigned short*)(ws + 16777216);  // 24 MiB, dead after QKV GEMM
    unsigned short* owb   = (unsigned short*)(ws + 41943040);  // 8 MiB
    unsigned short* qb    = (unsigned short*)(ws + 50331648);  // 16 MiB
    unsigned short* kb    = (unsigned short*)(ws + 67108864);  // 16 MiB
    unsigned short* vb    = (unsigned short*)(ws + 83886080);  // 16 MiB [B,H,S,D]
    unsigned short* vtb   = (unsigned short*)(ws + 0);         // alias xb (dead) [B,H,D,S]
    unsigned short* ctx   = (unsigned short*)(ws + 16777216);  // alias wqkvb (dead)

    cvt_f32_bf16<<<8192, 256, 0, stream>>>(x, xb, 8388608);
    cvt_f32_bf16<<<12288, 256, 0, stream>>>(wqkv_w, wqkvb, 12582912);
    cvt_f32_bf16<<<4096, 256, 0, stream>>>(out_w, owb, 4194304);

    // qkv = x @ wqkv_w^T + b  -> scatter q/k/v [B,H,S,D] (bf16)
    gemm_bt<1><<<dim3(48, 32), 256, 0, stream>>>(xb, wqkvb, wqkv_b, qb, kb, vb,
                                                 N3E, Ed);
    rope_qk<<<32768, 256, 0, stream>>>(qb, kb);
    transpose_v<<<dim3(64, 4, 32), dim3(32, 8), 0, stream>>>(vb, vtb);
    flash_attn<<<dim3(32, 32), 256, 0, stream>>>(qb, kb, vtb, ctx);
    // out = ctx @ out_w^T + b  (fp32)
    gemm_bt<0><<<dim3(16, 32), 256, 0, stream>>>(ctx, owb, out_b, out, nullptr,
                                                 nullptr, Ed, Ed);
}

// Round 4
// 350.795 us; speedup vs baseline: 1.4471x; 1.0622x over previous
//
#include <hip/hip_runtime.h>
#include <cstdint>
#include <cstddef>

// Problem constants (B,S,E,H)=(2,2048,2048,16), D=128, RD=128 (full-rotary)
#define Bd 2
#define Sd 2048
#define Ed 2048
#define Hd 16
#define Dd 128
#define N3E 6144
#define ATT_SCALE 0.08838834764831845f   // 1/sqrt(128)

typedef short bf16x8 __attribute__((ext_vector_type(8)));
typedef float f32x4 __attribute__((ext_vector_type(4)));

__device__ __forceinline__ float bf2f(unsigned short u) {
    union { unsigned int u; float f; } c;
    c.u = ((unsigned int)u) << 16;
    return c.f;
}
__device__ __forceinline__ unsigned short f2bf(float f) {
    union { float f; unsigned int u; } c;
    c.f = f;
    unsigned int x = c.u;
    x += 0x7FFFu + ((x >> 16) & 1u);   // RTNE (finite values only)
    return (unsigned short)(x >> 16);
}

__device__ __forceinline__ void gl2lds16(const void* g, void* l) {
    __builtin_amdgcn_global_load_lds(
        (const __attribute__((address_space(1))) void*)g,
        (__attribute__((address_space(3))) void*)l, 16, 0, 0);
}

// ---------------- fp32 -> bf16 convert (x, wqkv_w, out_w in one launch) ----
__global__ void cvt_all(const float* __restrict__ x,
                        const float* __restrict__ w1,
                        const float* __restrict__ w2,
                        unsigned short* __restrict__ ox,
                        unsigned short* __restrict__ o1,
                        unsigned short* __restrict__ o2) {
    int i = (blockIdx.x * 256 + threadIdx.x) * 4;
    const float* s;
    unsigned short* d;
    int off;
    if (i < 8388608) { s = x; d = ox; off = i; }
    else if (i < 20971520) { s = w1; d = o1; off = i - 8388608; }
    else { s = w2; d = o2; off = i - 20971520; }
    const float4 v = *(const float4*)(s + off);
    d[off + 0] = f2bf(v.x);
    d[off + 1] = f2bf(v.y);
    d[off + 2] = f2bf(v.z);
    d[off + 3] = f2bf(v.w);
}

// ---------------- bf16 MFMA GEMM, C = A * B^T + bias ----------------
// A: M x K (K contig), Bm: N x K (K contig). 128x128 tile, BK=64, 4 waves (2x2 of 64x64).
// XOR-swizzled LDS (8 chunks/row of 16B) so frag ds_read_b128 is 2-way (free).
// MODE 0: fp32 row-major out (o0), Ndim cols.
// MODE 1: fused QKV epilogue. Each 128-col tile = one head (D=128) of q/k/v:
//   tile -> LDS (bf16, stride 130), then q/k: RoPE + store [B,H,S,D];
//   v: transpose via column gather -> [B,H,D,S]. Saves 2 kernels + 96 MB traffic.
template <int MODE>
__global__ void gemm_bt(const unsigned short* __restrict__ A,
                        const unsigned short* __restrict__ Bm,
                        const float* __restrict__ bias,
                        void* __restrict__ o0, void* __restrict__ o1,
                        void* __restrict__ o2, int Ndim, int K) {
    // union: staging (As 16KB + Bs 16KB) / epilogue tile 128x130 bf16 (33,280B)
    __shared__ __align__(16) unsigned short U[16640];
    unsigned short* As = U;
    unsigned short* Bs = U + 8192;

    const int tid = threadIdx.x;
    const int lane = tid & 63;
    const int wave = tid >> 6;
    const int quad = lane >> 4;
    const int l16 = lane & 15;
    const int wr = wave >> 1;
    const int wc = wave & 1;

    const int n0 = blockIdx.x * 128;
    const int m0 = blockIdx.y * 128;

    const unsigned short* Ab = A + (size_t)m0 * K;
    const unsigned short* Bb = Bm + (size_t)n0 * K;

    const f32x4 fzero = {0.f, 0.f, 0.f, 0.f};
    f32x4 acc[4][4];
#pragma unroll
    for (int i = 0; i < 4; i++)
#pragma unroll
        for (int j = 0; j < 4; j++) acc[i][j] = fzero;

    for (int k0 = 0; k0 < K; k0 += 64) {
        __syncthreads();
#pragma unroll
        for (int it = 0; it < 4; ++it) {
            int L = it * 256 + tid;
            int row = L >> 3;
            int cs = L & 7;
            int gc = cs ^ (row & 7);
            gl2lds16(Ab + row * K + k0 + gc * 8, (void*)(As + L * 8));
            gl2lds16(Bb + row * K + k0 + gc * 8, (void*)(Bs + L * 8));
        }
        __syncthreads();
#pragma unroll
        for (int kk = 0; kk < 2; ++kk) {
            bf16x8 af[4], bfr[4];
#pragma unroll
            for (int i = 0; i < 4; i++) {
                int row = wr * 64 + i * 16 + l16;
                int cs = kk * 4 + quad;
                af[i] = *(const bf16x8*)(As + row * 64 + (cs ^ (row & 7)) * 8);
            }
#pragma unroll
            for (int j = 0; j < 4; j++) {
                int row = wc * 64 + j * 16 + l16;
                int cs = kk * 4 + quad;
                bfr[j] = *(const bf16x8*)(Bs + row * 64 + (cs ^ (row & 7)) * 8);
            }
#pragma unroll
            for (int i = 0; i < 4; i++)
#pragma unroll
                for (int j = 0; j < 4; j++)
                    acc[i][j] = __builtin_amdgcn_mfma_f32_16x16x32_bf16(
                        af[i], bfr[j], acc[i][j], 0, 0, 0);
        }
    }

    if (MODE == 0) {
#pragma unroll
        for (int j = 0; j < 4; j++) {
            int col = n0 + wc * 64 + j * 16 + l16;
            float bv = bias[col];
#pragma unroll
            for (int i = 0; i < 4; i++) {
                int rbase = m0 + wr * 64 + i * 16 + quad * 4;
#pragma unroll
                for (int r = 0; r < 4; r++)
                    ((float*)o0)[(size_t)(rbase + r) * Ndim + col] =
                        acc[i][j][r] + bv;
            }
        }
    } else {
        // ---- fused QKV epilogue ----
        __syncthreads();  // all frag reads of As/Bs done before tile overwrite
#pragma unroll
        for (int j = 0; j < 4; j++) {
            int coll = wc * 64 + j * 16 + l16;   // tile-local col = d
            float bv = bias[n0 + coll];
#pragma unroll
            for (int i = 0; i < 4; i++) {
                int rl = wr * 64 + i * 16 + quad * 4;
#pragma unroll
                for (int r = 0; r < 4; r++)
                    U[(rl + r) * 130 + coll] = f2bf(acc[i][j][r] + bv);
            }
        }
        __syncthreads();

        const int ch = n0 >> 7;         // 0..47
        const int c = ch >> 4;          // 0=q 1=k 2=v
        const int h = ch & 15;
        const int bb = m0 >> 11;        // batch (tile never crosses: 2048%128==0)
        const int s0 = m0 & 2047;

        if (c < 2) {
            unsigned short* dstq = (unsigned short*)(c == 0 ? o0 : o1);
            const size_t hb = ((size_t)(bb * Hd + h)) * Sd;
#pragma unroll
            for (int it = 0; it < 16; ++it) {
                int lin = it * 256 + tid;        // 128 rows x 32 d-pairs
                int row = lin >> 5, p = lin & 31;
                int s = s0 + row;
                unsigned int lo = *(const unsigned int*)(U + row * 130 + 2 * p);
                unsigned int hi =
                    *(const unsigned int*)(U + row * 130 + 64 + 2 * p);
                float v1a = bf2f((unsigned short)lo), v1b = bf2f(lo >> 16);
                float v2a = bf2f((unsigned short)hi), v2b = bf2f(hi >> 16);
                // theta_j = s * 10000^(-j/64),  j = 2p, 2p+1
                float fa = (float)s * __expf(-(float)(2 * p) *
                                             (9.210340371976184f / 64.0f));
                float fb = (float)s * __expf(-(float)(2 * p + 1) *
                                             (9.210340371976184f / 64.0f));
                float sna, csa, snb, csb;
                __sincosf(fa, &sna, &csa);
                __sincosf(fb, &snb, &csb);
                ushort2 r1, r2;
                r1.x = f2bf(v1a * csa - v2a * sna);
                r1.y = f2bf(v1b * csb - v2b * snb);
                r2.x = f2bf(v1a * sna + v2a * csa);
                r2.y = f2bf(v1b * snb + v2b * csb);
                unsigned short* dst = dstq + (hb + s) * Dd;
                *(ushort2*)(dst + 2 * p) = r1;
                *(ushort2*)(dst + 64 + 2 * p) = r2;
            }
        } else {
            unsigned short* dstv = (unsigned short*)o2;
            const size_t hb = ((size_t)(bb * Hd + h)) * Dd;
#pragma unroll
            for (int it = 0; it < 16; ++it) {
                int lin = it * 256 + tid;        // 128 d x 32 s-chunks
                int d = lin >> 5, sc = lin & 31;
                int s4 = sc * 4;
                ushort4 pk;
                pk.x = U[(s4 + 0) * 130 + d];
                pk.y = U[(s4 + 1) * 130 + d];
                pk.z = U[(s4 + 2) * 130 + d];
                pk.w = U[(s4 + 3) * 130 + d];
                *(ushort4*)(dstv + (hb + d) * Sd + s0 + s4) = pk;
            }
        }
    }
}

// ---------------- flash attention (causal, online softmax) ----------------
// BM=64 (16 q-rows/wave), BN=64, D=128. LDS = 40 KB -> 4 blocks/CU.
// S^T = K*Q^T so softmax rows live along lane&15 (q) with k in registers ->
// register reductions + 2 shfl_xor total. alpha/l broadcast via shfl.
// Layouts (verified): A[m=lane&15][k=quad*8+j]; B[n=lane&15][k=quad*8+j];
// C/D row=quad*4+reg, col=lane&15.
__global__ __launch_bounds__(256, 4) void flash_attn(
    const unsigned short* __restrict__ q, const unsigned short* __restrict__ k,
    const unsigned short* __restrict__ vt, unsigned short* __restrict__ ctx) {
    __shared__ __align__(16) unsigned short Ks[64 * 128];   // 16 KB [t][d] swizzled (Q stages here first)
    __shared__ __align__(16) unsigned short Vts[128 * 64];  // 16 KB [d][t] swizzled
    __shared__ __align__(16) unsigned short Ps[64 * 64];    // 8 KB  [q][t] chunk-swizzled

    const int tid = threadIdx.x;
    const int lane = tid & 63;
    const int wave = tid >> 6;
    const int quad = lane >> 4;
    const int l16 = lane & 15;
    const int rw0 = wave * 16;
    const int ql = rw0 + l16;        // this lane's q row (local)
    const int qsw = ql & 7;          // P-region swizzle key

    // balanced qi permutation: under round-robin block->CU placement the 4
    // blocks a CU receives have qi in {31-y0, y0, 23-y0, 8+y0} -> work sum 66
    // (constant). Heaviest quartile (k=0) dispatches first.
    const int yy = blockIdx.y;
    const int kq = yy >> 3, y0 = yy & 7;
    const int qi = (kq == 0) ? 31 - y0 : (kq == 1) ? y0 : (kq == 2) ? 23 - y0 : 8 + y0;
    const int bh = blockIdx.x;
    const int q0 = qi * 64;

    const unsigned short* qb = q + ((size_t)bh * Sd + q0) * Dd;
    const unsigned short* kb = k + (size_t)bh * Sd * Dd;
    const unsigned short* vtb = vt + (size_t)bh * Dd * Sd;

    // stage Q tile through Ks (64 rows x 16 chunks of 16B, XOR swizzle row&15)
#pragma unroll
    for (int it = 0; it < 4; ++it) {
        int L = it * 256 + tid;
        int row = L >> 4;
        int cs = L & 15;
        int gc = cs ^ (row & 15);
        gl2lds16(qb + row * Dd + gc * 8, (void*)(Ks + L * 8));
    }
    __syncthreads();
    bf16x8 aq[4];
#pragma unroll
    for (int kk = 0; kk < 4; kk++)
        aq[kk] = *(const bf16x8*)(Ks + ql * 128 + ((kk * 4 + quad) ^ (ql & 15)) * 8);
    __syncthreads();  // Q frags in registers; Ks free for K tiles

    const f32x4 fzero = {0.f, 0.f, 0.f, 0.f};
    f32x4 o[8];
#pragma unroll
    for (int jd = 0; jd < 8; jd++) o[jd] = fzero;
    float mi = -3.0e38f, li = 0.f;   // per-lane: online-softmax state of q row l16-of-wave

    for (int t0 = 0; t0 <= q0; t0 += 64) {
        // stage K tile [t][d] (16 chunks/row) and Vt tile [d][t] (8 chunks/row)
#pragma unroll
        for (int it = 0; it < 4; ++it) {
            int L = it * 256 + tid;
            int rk = L >> 4;
            int ck = L & 15;
            int gk = ck ^ (rk & 15);
            gl2lds16(kb + (size_t)(t0 + rk) * Dd + gk * 8, (void*)(Ks + L * 8));
            int rv = L >> 3;
            int cv = L & 7;
            int gv = cv ^ (rv & 7);
            gl2lds16(vtb + (size_t)rv * Sd + t0 + gv * 8, (void*)(Vts + L * 8));
        }
        __syncthreads();

        // S^T = K Q^T : sa[j] rows k=j*16+quad*4+r, col q=l16
        f32x4 sa[4];
#pragma unroll
        for (int j = 0; j < 4; j++) sa[j] = fzero;
#pragma unroll
        for (int kk = 0; kk < 4; kk++) {
            bf16x8 bk[4];
#pragma unroll
            for (int j = 0; j < 4; j++) {
                int rowt = j * 16 + l16;
                bk[j] = *(const bf16x8*)(Ks + rowt * 128 +
                                         ((kk * 4 + quad) ^ (rowt & 15)) * 8);
            }
#pragma unroll
            for (int j = 0; j < 4; j++)
                sa[j] = __builtin_amdgcn_mfma_f32_16x16x32_bf16(bk[j], aq[kk],
                                                                sa[j], 0, 0, 0);
        }

        // scale (+ causal mask on diagonal tile)
#pragma unroll
        for (int j = 0; j < 4; j++)
#pragma unroll
            for (int r = 0; r < 4; r++) sa[j][r] *= ATT_SCALE;
        if (t0 == q0) {
            const int qg = rw0 + l16;               // q (tile-local)
#pragma unroll
            for (int j = 0; j < 4; j++)
#pragma unroll
                for (int r = 0; r < 4; r++)
                    if ((j * 16 + quad * 4 + r) > qg) sa[j][r] = -3.0e38f;
        }

        // online softmax: register reduce over 16 k-values, then 2 shfl_xor
        float mx = -3.0e38f;
#pragma unroll
        for (int j = 0; j < 4; j++)
#pragma unroll
            for (int r = 0; r < 4; r++) mx = fmaxf(mx, sa[j][r]);
        mx = fmaxf(mx, __shfl_xor(mx, 16, 64));
        mx = fmaxf(mx, __shfl_xor(mx, 32, 64));
        const float mnew = fmaxf(mi, mx);
        const float alpha = __expf(mi - mnew);
        float rs = 0.f;
#pragma unroll
        for (int j = 0; j < 4; j++)
#pragma unroll
            for (int r = 0; r < 4; r++) {
                float pp = __expf(sa[j][r] - mnew);
                sa[j][r] = pp;
                rs += pp;
            }
        rs += __shfl_xor(rs, 16, 64);
        rs += __shfl_xor(rs, 32, 64);
        li = li * alpha + rs;
        mi = mnew;

        // P store: lane owns row ql, k = j*16+quad*4+{0..3} -> packed b64.
        // chunk c = j*2+(quad>>1), swizzled c^qsw; inner (quad&1)*4 ushorts.
#pragma unroll
        for (int j = 0; j < 4; j++) {
            ushort4 pk;
            pk.x = f2bf(sa[j][0]);
            pk.y = f2bf(sa[j][1]);
            pk.z = f2bf(sa[j][2]);
            pk.w = f2bf(sa[j][3]);
            *(ushort4*)(Ps + ql * 64 + ((j * 2 + (quad >> 1)) ^ qsw) * 8 +
                        (quad & 1) * 4) = pk;
        }

        // broadcast alpha to O layout rows (q = quad*4+r) via shfl
        float av[4];
#pragma unroll
        for (int r = 0; r < 4; r++) av[r] = __shfl(alpha, quad * 4 + r, 64);
#pragma unroll
        for (int jd = 0; jd < 8; jd++)
#pragma unroll
            for (int r = 0; r < 4; r++) o[jd][r] *= av[r];

        // O += P * V   (wave-local P rows; no barrier needed before reads)
#pragma unroll
        for (int kk = 0; kk < 2; kk++) {
            bf16x8 ap = *(const bf16x8*)(Ps + ql * 64 +
                                         ((kk * 4 + quad) ^ qsw) * 8);
            bf16x8 bv[8];
#pragma unroll
            for (int jd = 0; jd < 8; jd++) {
                int d = jd * 16 + l16;
                bv[jd] = *(const bf16x8*)(Vts + d * 64 +
                                          ((kk * 4 + quad) ^ (d & 7)) * 8);
            }
#pragma unroll
            for (int jd = 0; jd < 8; jd++)
                o[jd] = __builtin_amdgcn_mfma_f32_16x16x32_bf16(ap, bv[jd],
                                                                o[jd], 0, 0, 0);
        }
        __syncthreads();  // protect Ks/Vts before next-tile staging
    }

    // epilogue: ctx[b, s, h*D+d] = O / l   (bf16)
    const int b = bh >> 4;
    const int h = bh & 15;
    float linv[4];
#pragma unroll
    for (int r = 0; r < 4; r++) linv[r] = 1.0f / __shfl(li, quad * 4 + r, 64);
#pragma unroll
    for (int r = 0; r < 4; r++) {
        const int grow = q0 + rw0 + quad * 4 + r;
        unsigned short* dst = ctx + ((size_t)(b * Sd + grow)) * Ed + h * Dd;
#pragma unroll
        for (int jd = 0; jd < 8; jd++)
            dst[jd * 16 + l16] = f2bf(o[jd][r] * linv[r]);
    }
}

extern "C" void kernel_launch(void* const* d_in, const int* in_sizes, int n_in,
                              void* d_out, int out_size, void* d_ws,
                              size_t ws_size, hipStream_t stream) {
    const float* x = (const float*)d_in[0];
    const float* wqkv_w = (const float*)d_in[1];
    const float* wqkv_b = (const float*)d_in[2];
    const float* out_w = (const float*)d_in[3];
    const float* out_b = (const float*)d_in[4];
    float* out = (float*)d_out;

    // workspace layout (bytes); total 100,663,296 (96 MiB)
    char* ws = (char*)d_ws;
    unsigned short* xb    = (unsigned short*)(ws + 0);         // 16 MiB, dead after QKV GEMM
    unsigned short* wqkvb = (unsigned short*)(ws + 16777216);  // 24 MiB
    unsigned short* owb   = (unsigned short*)(ws + 41943040);  // 8 MiB
    unsigned short* qb    = (unsigned short*)(ws + 50331648);  // 16 MiB [B,H,S,D]
    unsigned short* kb    = (unsigned short*)(ws + 67108864);  // 16 MiB [B,H,S,D]
    unsigned short* vtb   = (unsigned short*)(ws + 83886080);  // 16 MiB [B,H,D,S]
    unsigned short* ctx   = (unsigned short*)(ws + 0);         // alias xb (dead)

    cvt_all<<<24576, 256, 0, stream>>>(x, wqkv_w, out_w, xb, wqkvb, owb);
    // qkv = x @ wqkv_w^T + b, fused RoPE (q,k) + V-transpose in epilogue
    gemm_bt<1><<<dim3(48, 32), 256, 0, stream>>>(xb, wqkvb, wqkv_b, qb, kb, vtb,
                                                 N3E, Ed);
    flash_attn<<<dim3(32, 32), 256, 0, stream>>>(qb, kb, vtb, ctx);
    // out = ctx @ out_w^T + b  (fp32)
    gemm_bt<0><<<dim3(16, 32), 256, 0, stream>>>(ctx, owb, out_b, out, nullptr,
                                                 nullptr, Ed, Ed);
}

// Round 6
// 348.455 us; speedup vs baseline: 1.4568x; 1.0067x over previous
//
#include <hip/hip_runtime.h>
#include <cstdint>
#include <cstddef>

// Problem constants (B,S,E,H)=(2,2048,2048,16), D=128, RD=128 (full-rotary)
#define Bd 2
#define Sd 2048
#define Ed 2048
#define Hd 16
#define Dd 128
#define N3E 6144
#define ATT_SCALE 0.08838834764831845f   // 1/sqrt(128)

typedef short bf16x8 __attribute__((ext_vector_type(8)));
typedef float f32x4 __attribute__((ext_vector_type(4)));
typedef float f32x16 __attribute__((ext_vector_type(16)));

__device__ __forceinline__ float bf2f(unsigned short u) {
    union { unsigned int u; float f; } c;
    c.u = ((unsigned int)u) << 16;
    return c.f;
}
__device__ __forceinline__ unsigned short f2bf(float f) {
    union { float f; unsigned int u; } c;
    c.f = f;
    unsigned int x = c.u;
    x += 0x7FFFu + ((x >> 16) & 1u);   // RTNE (finite values only)
    return (unsigned short)(x >> 16);
}

__device__ __forceinline__ void gl2lds16(const void* g, void* l) {
    __builtin_amdgcn_global_load_lds(
        (const __attribute__((address_space(1))) void*)g,
        (__attribute__((address_space(3))) void*)l, 16, 0, 0);
}

// ---------------- fp32 -> bf16 convert (x, wqkv_w, out_w in one launch) ----
__global__ void cvt_all(const float* __restrict__ x,
                        const float* __restrict__ w1,
                        const float* __restrict__ w2,
                        unsigned short* __restrict__ ox,
                        unsigned short* __restrict__ o1,
                        unsigned short* __restrict__ o2) {
    int i = (blockIdx.x * 256 + threadIdx.x) * 4;
    const float* s;
    unsigned short* d;
    int off;
    if (i < 8388608) { s = x; d = ox; off = i; }
    else if (i < 20971520) { s = w1; d = o1; off = i - 8388608; }
    else { s = w2; d = o2; off = i - 20971520; }
    const float4 v = *(const float4*)(s + off);
    d[off + 0] = f2bf(v.x);
    d[off + 1] = f2bf(v.y);
    d[off + 2] = f2bf(v.z);
    d[off + 3] = f2bf(v.w);
}

// ---------------- bf16 MFMA GEMM, C = A * B^T + bias ----------------
// A: M x K (K contig), Bm: N x K (K contig). 128x128 tile, BK=64, 4 waves (2x2 of 64x64).
// XOR-swizzled LDS (8 chunks/row of 16B) so frag ds_read_b128 is 2-way (free).
// MODE 0: fp32 row-major out (o0), Ndim cols.
// MODE 1: fused QKV epilogue. Each 128-col tile = one head (D=128) of q/k/v:
//   tile -> LDS (bf16, stride 130), then q/k: RoPE + store [B,H,S,D];
//   v: transpose via column gather -> [B,H,D,S].
template <int MODE>
__global__ void gemm_bt(const unsigned short* __restrict__ A,
                        const unsigned short* __restrict__ Bm,
                        const float* __restrict__ bias,
                        void* __restrict__ o0, void* __restrict__ o1,
                        void* __restrict__ o2, int Ndim, int K) {
    // union: staging (As 16KB + Bs 16KB) / epilogue tile 128x130 bf16 (33,280B)
    __shared__ __align__(16) unsigned short U[16640];
    unsigned short* As = U;
    unsigned short* Bs = U + 8192;

    const int tid = threadIdx.x;
    const int lane = tid & 63;
    const int wave = tid >> 6;
    const int quad = lane >> 4;
    const int l16 = lane & 15;
    const int wr = wave >> 1;
    const int wc = wave & 1;

    const int n0 = blockIdx.x * 128;
    const int m0 = blockIdx.y * 128;

    const unsigned short* Ab = A + (size_t)m0 * K;
    const unsigned short* Bb = Bm + (size_t)n0 * K;

    const f32x4 fzero = {0.f, 0.f, 0.f, 0.f};
    f32x4 acc[4][4];
#pragma unroll
    for (int i = 0; i < 4; i++)
#pragma unroll
        for (int j = 0; j < 4; j++) acc[i][j] = fzero;

    for (int k0 = 0; k0 < K; k0 += 64) {
        __syncthreads();
#pragma unroll
        for (int it = 0; it < 4; ++it) {
            int L = it * 256 + tid;
            int row = L >> 3;
            int cs = L & 7;
            int gc = cs ^ (row & 7);
            gl2lds16(Ab + row * K + k0 + gc * 8, (void*)(As + L * 8));
            gl2lds16(Bb + row * K + k0 + gc * 8, (void*)(Bs + L * 8));
        }
        __syncthreads();
#pragma unroll
        for (int kk = 0; kk < 2; ++kk) {
            bf16x8 af[4], bfr[4];
#pragma unroll
            for (int i = 0; i < 4; i++) {
                int row = wr * 64 + i * 16 + l16;
                int cs = kk * 4 + quad;
                af[i] = *(const bf16x8*)(As + row * 64 + (cs ^ (row & 7)) * 8);
            }
#pragma unroll
            for (int j = 0; j < 4; j++) {
                int row = wc * 64 + j * 16 + l16;
                int cs = kk * 4 + quad;
                bfr[j] = *(const bf16x8*)(Bs + row * 64 + (cs ^ (row & 7)) * 8);
            }
#pragma unroll
            for (int i = 0; i < 4; i++)
#pragma unroll
                for (int j = 0; j < 4; j++)
                    acc[i][j] = __builtin_amdgcn_mfma_f32_16x16x32_bf16(
                        af[i], bfr[j], acc[i][j], 0, 0, 0);
        }
    }

    if (MODE == 0) {
#pragma unroll
        for (int j = 0; j < 4; j++) {
            int col = n0 + wc * 64 + j * 16 + l16;
            float bv = bias[col];
#pragma unroll
            for (int i = 0; i < 4; i++) {
                int rbase = m0 + wr * 64 + i * 16 + quad * 4;
#pragma unroll
                for (int r = 0; r < 4; r++)
                    ((float*)o0)[(size_t)(rbase + r) * Ndim + col] =
                        acc[i][j][r] + bv;
            }
        }
    } else {
        // ---- fused QKV epilogue ----
        __syncthreads();  // all frag reads of As/Bs done before tile overwrite
#pragma unroll
        for (int j = 0; j < 4; j++) {
            int coll = wc * 64 + j * 16 + l16;   // tile-local col = d
            float bv = bias[n0 + coll];
#pragma unroll
            for (int i = 0; i < 4; i++) {
                int rl = wr * 64 + i * 16 + quad * 4;
#pragma unroll
                for (int r = 0; r < 4; r++)
                    U[(rl + r) * 130 + coll] = f2bf(acc[i][j][r] + bv);
            }
        }
        __syncthreads();

        const int ch = n0 >> 7;         // 0..47
        const int c = ch >> 4;          // 0=q 1=k 2=v
        const int h = ch & 15;
        const int bb = m0 >> 11;        // batch (tile never crosses: 2048%128==0)
        const int s0 = m0 & 2047;

        if (c < 2) {
            unsigned short* dstq = (unsigned short*)(c == 0 ? o0 : o1);
            const size_t hb = ((size_t)(bb * Hd + h)) * Sd;
#pragma unroll
            for (int it = 0; it < 16; ++it) {
                int lin = it * 256 + tid;        // 128 rows x 32 d-pairs
                int row = lin >> 5, p = lin & 31;
                int s = s0 + row;
                unsigned int lo = *(const unsigned int*)(U + row * 130 + 2 * p);
                unsigned int hi =
                    *(const unsigned int*)(U + row * 130 + 64 + 2 * p);
                float v1a = bf2f((unsigned short)lo), v1b = bf2f(lo >> 16);
                float v2a = bf2f((unsigned short)hi), v2b = bf2f(hi >> 16);
                // theta_j = s * 10000^(-j/64),  j = 2p, 2p+1
                float fa = (float)s * __expf(-(float)(2 * p) *
                                             (9.210340371976184f / 64.0f));
                float fb = (float)s * __expf(-(float)(2 * p + 1) *
                                             (9.210340371976184f / 64.0f));
                float sna, csa, snb, csb;
                __sincosf(fa, &sna, &csa);
                __sincosf(fb, &snb, &csb);
                ushort2 r1, r2;
                r1.x = f2bf(v1a * csa - v2a * sna);
                r1.y = f2bf(v1b * csb - v2b * snb);
                r2.x = f2bf(v1a * sna + v2a * csa);
                r2.y = f2bf(v1b * snb + v2b * csb);
                unsigned short* dst = dstq + (hb + s) * Dd;
                *(ushort2*)(dst + 2 * p) = r1;
                *(ushort2*)(dst + 64 + 2 * p) = r2;
            }
        } else {
            unsigned short* dstv = (unsigned short*)o2;
            const size_t hb = ((size_t)(bb * Hd + h)) * Dd;
#pragma unroll
            for (int it = 0; it < 16; ++it) {
                int lin = it * 256 + tid;        // 128 d x 32 s-chunks
                int d = lin >> 5, sc = lin & 31;
                int s4 = sc * 4;
                ushort4 pk;
                pk.x = U[(s4 + 0) * 130 + d];
                pk.y = U[(s4 + 1) * 130 + d];
                pk.z = U[(s4 + 2) * 130 + d];
                pk.w = U[(s4 + 3) * 130 + d];
                *(ushort4*)(dstv + (hb + d) * Sd + s0 + s4) = pk;
            }
        }
    }
}

// ---------------- flash attention (causal, online softmax) ----------------
// 32x32x16 MFMA, BM=128 (32 q/wave), BN=64. S^T = K*Q^T with Q in registers;
// O^T = Vt*P^T. C/D col = q = lane&31 -> softmax and alpha/li rescale fully
// lane-local (1 shfl_xor per reduction). R6 fixes vs R5: Ps is 128x64 with
// XOR-chunk swizzle so every ds access is naturally aligned (R5's stride-68
// made odd rows' ds_read_b128 misaligned = UB), and an explicit barrier
// between P-store and PV-read.
// 32x32 layouts (verified m74/m101 + R5 pass): A/B [n=lane&31][k=(lane>>5)*8+j];
// C/D col=lane&31, row=(reg&3)+8*(reg>>2)+4*(lane>>5).
__global__ __launch_bounds__(256, 2) void flash_attn(
    const unsigned short* __restrict__ q, const unsigned short* __restrict__ k,
    const unsigned short* __restrict__ vt, unsigned short* __restrict__ ctx) {
    __shared__ __align__(16) unsigned short Ks[64 * 128];   // 16 KB [t][d], 16 chunks/row, xor row&15
    __shared__ __align__(16) unsigned short Vts[128 * 64];  // 16 KB [d][t], 8 chunks/row, xor row&7
    __shared__ __align__(16) unsigned short Ps[128 * 64];   // 16 KB [q][t], 8 chunks/row, xor row&7

    const int tid = threadIdx.x;
    const int lane = tid & 63;
    const int wave = tid >> 6;
    const int l32 = lane & 31;
    const int half = lane >> 5;

    // qi pairing: CU gets blocks y and y+8 (round-robin, 512 blocks / 256 CU)
    // -> qi {15-y, y}: per-CU tile count constant (34).
    const int yy = blockIdx.y;
    const int qi = (yy < 8) ? 15 - yy : yy - 8;
    const int bh = blockIdx.x;
    const int q0 = qi * 128;
    const int qg = q0 + wave * 32 + l32;        // this lane's global q row
    const int prow = wave * 32 + l32;           // P row (q local)
    const int psw = prow & 7;                   // P swizzle key

    const unsigned short* kb = k + (size_t)bh * Sd * Dd;
    const unsigned short* vtb = vt + (size_t)bh * Dd * Sd;

    // Q fragments straight from global: lane owns row qg, frag ks covers
    // d = ks*16 + half*8 + {0..7}  (B-operand layout), 8 x 16B loads.
    bf16x8 aq[8];
    {
        const unsigned short* qrow = q + ((size_t)bh * Sd + qg) * Dd;
#pragma unroll
        for (int ks = 0; ks < 8; ks++)
            aq[ks] = *(const bf16x8*)(qrow + ks * 16 + half * 8);
    }

    f32x16 o[4];   // O^T: d-block db: row d = db*32+(r&3)+8*(r>>2)+4*half, col q=l32
#pragma unroll
    for (int db = 0; db < 4; db++)
#pragma unroll
        for (int r = 0; r < 16; r++) o[db][r] = 0.f;
    float mi = -3.0e38f, li = 0.f;

    const int tmax = q0 + 64;
    for (int t0 = 0; t0 <= tmax; t0 += 64) {
        // stage K [64t][128d] and Vt [128d][64t], 1024 16B-chunks each
#pragma unroll
        for (int it = 0; it < 4; ++it) {
            int L = it * 256 + tid;
            int rk = L >> 4;
            int ck = L & 15;
            int gk = ck ^ (rk & 15);
            gl2lds16(kb + (size_t)(t0 + rk) * Dd + gk * 8, (void*)(Ks + L * 8));
            int rv = L >> 3;
            int cv = L & 7;
            int gv = cv ^ (rv & 7);
            gl2lds16(vtb + (size_t)rv * Sd + t0 + gv * 8, (void*)(Vts + L * 8));
        }
        __syncthreads();

        // S^T = K * Q^T : 2 t-blocks of 32, contraction d=128 (8 ksteps)
        f32x16 sa[2];
#pragma unroll
        for (int b2 = 0; b2 < 2; b2++)
#pragma unroll
            for (int r = 0; r < 16; r++) sa[b2][r] = 0.f;
#pragma unroll
        for (int ks = 0; ks < 8; ks++) {
            int cd = ks * 2 + half;
#pragma unroll
            for (int b2 = 0; b2 < 2; b2++) {
                int row = b2 * 32 + l32;
                bf16x8 ak = *(const bf16x8*)(Ks + row * 128 +
                                             (cd ^ (row & 15)) * 8);
                sa[b2] = __builtin_amdgcn_mfma_f32_32x32x16_bf16(ak, aq[ks],
                                                                 sa[b2], 0, 0, 0);
            }
        }

        // scale + causal mask; per-lane row max over 32 reg values + 1 shfl
        float mx = -3.0e38f;
#pragma unroll
        for (int b2 = 0; b2 < 2; b2++)
#pragma unroll
            for (int r = 0; r < 16; r++) {
                float v = sa[b2][r] * ATT_SCALE;
                int tg = t0 + b2 * 32 + (r & 3) + 8 * (r >> 2) + 4 * half;
                if (tg > qg) v = -3.0e38f;
                sa[b2][r] = v;
                mx = fmaxf(mx, v);
            }
        mx = fmaxf(mx, __shfl_xor(mx, 32, 64));
        const float mnew = fmaxf(mi, mx);
        const float alpha = __expf(mi - mnew);
        float rs = 0.f;
#pragma unroll
        for (int b2 = 0; b2 < 2; b2++)
#pragma unroll
            for (int r = 0; r < 16; r++) {
                float pp = __expf(sa[b2][r] - mnew);
                sa[b2][r] = pp;
                rs += pp;
            }
        rs += __shfl_xor(rs, 32, 64);
        li = li * alpha + rs;
        mi = mnew;

        // rescale O (fully in-lane: O^T col q == softmax lane q)
#pragma unroll
        for (int db = 0; db < 4; db++)
#pragma unroll
            for (int r = 0; r < 16; r++) o[db][r] *= alpha;

        // P store: row prow holds P[q][t] in t-order, 8 chunks of 8 ushorts,
        // chunk XOR-swizzled by prow&7. reg (b2,g) -> t = b2*32+8g+4*half+{0..3}
        // -> chunk b2*4+g, within-chunk half*4: 8B-aligned ds_write_b64.
#pragma unroll
        for (int b2 = 0; b2 < 2; b2++)
#pragma unroll
            for (int g = 0; g < 4; g++) {
                ushort4 pk;
                pk.x = f2bf(sa[b2][g * 4 + 0]);
                pk.y = f2bf(sa[b2][g * 4 + 1]);
                pk.z = f2bf(sa[b2][g * 4 + 2]);
                pk.w = f2bf(sa[b2][g * 4 + 3]);
                *(ushort4*)(Ps + prow * 64 + ((b2 * 4 + g) ^ psw) * 8 +
                            half * 4) = pk;
            }
        __syncthreads();  // P visible (and guards vs any cross-lane timing)

        // O^T += Vt * P^T : 4 d-blocks, contraction t=64 (4 ksteps)
        // bp chunk = kk*2+half -> t = kk*16+half*8+{0..7}: 16B-aligned b128.
#pragma unroll
        for (int kk = 0; kk < 4; kk++) {
            bf16x8 bp = *(const bf16x8*)(Ps + prow * 64 +
                                         ((kk * 2 + half) ^ psw) * 8);
#pragma unroll
            for (int db = 0; db < 4; db++) {
                int row = db * 32 + l32;
                bf16x8 av = *(const bf16x8*)(
                    Vts + row * 64 + ((kk * 2 + half) ^ (row & 7)) * 8);
                o[db] = __builtin_amdgcn_mfma_f32_32x32x16_bf16(av, bp, o[db],
                                                                0, 0, 0);
            }
        }
        __syncthreads();  // protect Ks/Vts/Ps before next-tile staging
    }

    // epilogue: ctx[b, qg, h*128+d] = O^T[d][qg] / li  (bf16, ushort4 groups)
    const int b = bh >> 4;
    const int h = bh & 15;
    const float inv = 1.0f / li;
    unsigned short* dst = ctx + ((size_t)(b * Sd + qg)) * Ed + h * Dd;
#pragma unroll
    for (int db = 0; db < 4; db++)
#pragma unroll
        for (int g = 0; g < 4; g++) {
            ushort4 pk;
            pk.x = f2bf(o[db][g * 4 + 0] * inv);
            pk.y = f2bf(o[db][g * 4 + 1] * inv);
            pk.z = f2bf(o[db][g * 4 + 2] * inv);
            pk.w = f2bf(o[db][g * 4 + 3] * inv);
            *(ushort4*)(dst + db * 32 + g * 8 + half * 4) = pk;
        }
}

extern "C" void kernel_launch(void* const* d_in, const int* in_sizes, int n_in,
                              void* d_out, int out_size, void* d_ws,
                              size_t ws_size, hipStream_t stream) {
    const float* x = (const float*)d_in[0];
    const float* wqkv_w = (const float*)d_in[1];
    const float* wqkv_b = (const float*)d_in[2];
    const float* out_w = (const float*)d_in[3];
    const float* out_b = (const float*)d_in[4];
    float* out = (float*)d_out;

    // workspace layout (bytes); total 100,663,296 (96 MiB)
    char* ws = (char*)d_ws;
    unsigned short* xb    = (unsigned short*)(ws + 0);         // 16 MiB, dead after QKV GEMM
    unsigned short* wqkvb = (unsigned short*)(ws + 16777216);  // 24 MiB
    unsigned short* owb   = (unsigned short*)(ws + 41943040);  // 8 MiB
    unsigned short* qb    = (unsigned short*)(ws + 50331648);  // 16 MiB [B,H,S,D]
    unsigned short* kb    = (unsigned short*)(ws + 67108864);  // 16 MiB [B,H,S,D]
    unsigned short* vtb   = (unsigned short*)(ws + 83886080);  // 16 MiB [B,H,D,S]
    unsigned short* ctx   = (unsigned short*)(ws + 0);         // alias xb (dead)

    cvt_all<<<24576, 256, 0, stream>>>(x, wqkv_w, out_w, xb, wqkvb, owb);
    // qkv = x @ wqkv_w^T + b, fused RoPE (q,k) + V-transpose in epilogue
    gemm_bt<1><<<dim3(48, 32), 256, 0, stream>>>(xb, wqkvb, wqkv_b, qb, kb, vtb,
                                                 N3E, Ed);
    flash_attn<<<dim3(32, 16), 256, 0, stream>>>(qb, kb, vtb, ctx);
    // out = ctx @ out_w^T + b  (fp32)
    gemm_bt<0><<<dim3(16, 32), 256, 0, stream>>>(ctx, owb, out_b, out, nullptr,
                                                 nullptr, Ed, Ed);
}